// Round 10
// baseline (106.339 us; speedup 1.0000x reference)
//
#include <hip/hip_runtime.h>
#include <stdint.h>

#define B_N   4096
#define D_DIM 1024
#define INF_F 3.4e38f

typedef float floatx4 __attribute__((ext_vector_type(4)));

// ws layout (bytes):
//   [0]      u64   minpack[4096]
//   [32768]  u32   maxbits[4096]
//   [49152]  f32   norms[4096]
//   [65536]  u32   done            (64-B gap before ref_idx)
//   [65600]  i32   ref_idx[4096]
//   [131072] fp8   xq[4096*1024]  (4 MB)  -- K-BLOCKED PRE-SWIZZLED (R7 layout)
#define XQ_OFF 131072

// xq layout (R7, verified): kb = K-chunk 0..7 (128 B of K), g = row>>3,
// r3 = row&7, chunk c stored at slot c^r3:
//   byte_addr = (kb*512 + g)*1024 + r3*128 + (c^r3)*16 + (k&15)
// => staging GLDS for any 8-row group of one K-chunk is ONE contiguous 1 KB
//    run (per-lane src +lane*16), landing the verified LDS image.
__global__ __launch_bounds__(256)
void k_prep(const float* __restrict__ x, unsigned char* __restrict__ xq,
            float* __restrict__ norms,
            unsigned long long* __restrict__ minpack,
            unsigned int* __restrict__ maxbits,
            unsigned int* __restrict__ done) {
    const int row = blockIdx.x;
    const int t   = threadIdx.x;
    float4 v = ((const float4*)x)[row * 256 + t];
    int p = __builtin_amdgcn_cvt_pk_fp8_f32(v.x, v.y, 0, false);
    p     = __builtin_amdgcn_cvt_pk_fp8_f32(v.z, v.w, p, true);
    const int kb = t >> 5, c = (t >> 2) & 7, r3 = row & 7;
    ((int*)xq)[(kb * 512 + (row >> 3)) * 256 + r3 * 32 + (c ^ r3) * 4 + (t & 3)] = p;
    float sq = v.x * v.x + v.y * v.y + v.z * v.z + v.w * v.w;
    #pragma unroll
    for (int off = 32; off; off >>= 1) sq += __shfl_down(sq, off);
    __shared__ float ws4[4];
    if ((t & 63) == 0) ws4[t >> 6] = sq;
    __syncthreads();
    if (t == 0) {
        norms[row]   = ws4[0] + ws4[1] + ws4[2] + ws4[3];
        minpack[row] = 0xFFFFFFFFFFFFFFFFull;
        maxbits[row] = 0u;
        if (row == 0) *done = 0u;
    }
}

#define GLDS(g, l)                                                              \
    __builtin_amdgcn_global_load_lds(                                           \
        (__attribute__((address_space(1))) void*)(void*)(g),                    \
        (__attribute__((address_space(3))) void*)(void*)(l), 16, 0, 0)

// R10: pass1 = EXACT R7 kernel (verified, 99.3us total) + FUSED TAIL via the
// last-block-done pattern. Rationale: pass1's K-loop ~30us is invariant under
// every structural change (R3/R4/R7/R8/R9 all null) — the untouched budget is
// k_tail (1-block latency-bound) + its dispatch boundary (~10-20us combined).
// Each block: epilogue atomics -> threadfence -> atomicAdd(done). The block
// seeing old==527 acquires and runs the tail inline (512 thr, 8 elem/thr).
// No spin anywhere -> deadlock-free regardless of residency. minpack/maxbits
// read with agent-scope atomic loads (device-coherent, G16).
__global__ __launch_bounds__(512, 6)
void k_pass1_fp8(const unsigned char* __restrict__ xq,
                 const float* __restrict__ norms,
                 unsigned long long* __restrict__ minpack,
                 unsigned int* __restrict__ maxbits,
                 unsigned int* __restrict__ done,
                 const float* __restrict__ x,
                 const int* __restrict__ labels,
                 int* __restrict__ ref_idx,
                 float* __restrict__ out) {
    // linear block id -> (ti, tj), tj <= ti
    int bid = blockIdx.x;
    int ti  = (int)((sqrtf(8.f * bid + 1.f) - 1.f) * 0.5f);
    while ((ti + 1) * (ti + 2) / 2 <= bid) ti++;
    while (ti * (ti + 1) / 2 > bid) ti--;
    int tj  = bid - ti * (ti + 1) / 2;

    __shared__ unsigned char As[16384];      // 128 rows x 128 B (swizzled slots)
    __shared__ unsigned char Bs[16384];
    __shared__ unsigned long long redMin[128][2];
    __shared__ float redMax[128][2];

    const int t    = threadIdx.x;
    const int w    = t >> 6, lane = t & 63;   // 8 waves
    const int wm   = w >> 1, wn = w & 1;      // 32-row band x 64-col half
    const int q4   = lane >> 4, c15 = lane & 15;
    const int r7   = c15 & 7;
    const int i0   = ti * 128, j0 = tj * 128;

    // staging: instr e (= w*2+q) stages rows panel+e*8..+7 of the current
    // K-chunk; contiguous 1 KB source, per-lane +lane*16 (R7-verified).
    const unsigned char* gA[2]; const unsigned char* gB[2];
    unsigned char* lA[2]; unsigned char* lB[2];
    #pragma unroll
    for (int q = 0; q < 2; q++) {
        int e = w * 2 + q;
        gA[q] = xq + ((size_t)(i0 >> 3) + e) * 1024 + lane * 16;
        gB[q] = xq + ((size_t)(j0 >> 3) + e) * 1024 + lane * 16;
        lA[q] = As + e * 1024;
        lB[q] = Bs + e * 1024;
    }

    // fragment offsets (R7-verified)
    int oib[4];
    #pragma unroll
    for (int kk = 0; kk < 4; kk++) {
        int sl  = kk * 2 + (q4 >> 1);
        oib[kk] = (((sl ^ r7) << 4) | ((q4 & 1) << 3));
    }
    int rbA[2], rbB[4];
    #pragma unroll
    for (int st = 0; st < 2; st++) rbA[st] = (wm * 32 + st * 16 + c15) * 128;
    #pragma unroll
    for (int st = 0; st < 4; st++) rbB[st] = (wn * 64 + st * 16 + c15) * 128;

    floatx4 acc[2][4];
    #pragma unroll
    for (int m = 0; m < 2; m++)
        #pragma unroll
        for (int n = 0; n < 4; n++)
            acc[m][n] = (floatx4){0.f, 0.f, 0.f, 0.f};

    for (int it = 0; it < 8; it++) {         // K = 1024, BK = 128 fp8
        __syncthreads();
        #pragma unroll
        for (int q = 0; q < 2; q++) {
            GLDS(gA[q], lA[q]);
            GLDS(gB[q], lB[q]);
            gA[q] += 512 * 1024;             // next K-chunk (stride 512 KB)
            gB[q] += 512 * 1024;
        }
        __syncthreads();
        #pragma unroll
        for (int kk = 0; kk < 4; kk++) {
            long long af[2], bfr[4];
            #pragma unroll
            for (int st = 0; st < 2; st++)
                af[st]  = *(const long long*)(As + rbA[st] + oib[kk]);
            #pragma unroll
            for (int st = 0; st < 4; st++)
                bfr[st] = *(const long long*)(Bs + rbB[st] + oib[kk]);
            #pragma unroll
            for (int m = 0; m < 2; m++)
                #pragma unroll
                for (int n = 0; n < 4; n++)
                    acc[m][n] = __builtin_amdgcn_mfma_f32_16x16x32_fp8_fp8(
                        af[m], bfr[n], acc[m][n], 0, 0, 0);
        }
    }

    // epilogue: d2 = ni + nj - 2*dot (clamped >= 0), strictly j < i.
    float nj[4];
    #pragma unroll
    for (int st = 0; st < 4; st++) nj[st] = norms[j0 + wn * 64 + st * 16 + c15];

    #pragma unroll
    for (int st_m = 0; st_m < 2; st_m++) {
        #pragma unroll
        for (int r = 0; r < 4; r++) {
            int i_loc = wm * 32 + st_m * 16 + q4 * 4 + r;
            int gi    = i0 + i_loc;
            float ni  = norms[gi];
            unsigned long long mp = 0xFFFFFFFFFFFFFFFFull;
            float mx = -INF_F;
            #pragma unroll
            for (int st_n = 0; st_n < 4; st_n++) {
                int gj = j0 + wn * 64 + st_n * 16 + c15;
                if (gj < gi) {
                    float dot = acc[st_m][st_n][r];
                    float d2  = fmaxf(ni + nj[st_n] - 2.f * dot, 0.f);
                    unsigned long long p =
                        ((unsigned long long)__float_as_uint(d2) << 32) | (unsigned)gj;
                    if (p < mp) mp = p;
                    mx = fmaxf(mx, d2);
                }
            }
            #pragma unroll
            for (int off = 1; off < 16; off <<= 1) {
                unsigned long long op = __shfl_xor(mp, off, 64);
                if (op < mp) mp = op;
                float om = __shfl_xor(mx, off, 64);
                mx = fmaxf(mx, om);
            }
            if (c15 == 0) { redMin[i_loc][wn] = mp; redMax[i_loc][wn] = mx; }
        }
    }
    __syncthreads();
    if (t < 128) {
        unsigned long long mp = redMin[t][0];
        if (redMin[t][1] < mp) mp = redMin[t][1];
        float mx = fmaxf(redMax[t][0], redMax[t][1]);
        if (mp != 0xFFFFFFFFFFFFFFFFull) {
            atomicMin(&minpack[i0 + t], mp);
            atomicMax(&maxbits[i0 + t], __float_as_uint(mx));
        }
    }

    // ---- last-block-done handshake ----
    __syncthreads();
    __shared__ int sLast;
    if (t == 0) {
        __threadfence();                      // release: my atomics visible
        unsigned old = atomicAdd(done, 1u);
        sLast = (old == 527u);
    }
    __syncthreads();
    if (!sLast) return;
    __threadfence();                          // acquire: see all blocks' atomics

    // ---- FUSED TAIL (512 threads, 8 elements/thread) ----
    const int wid8 = t >> 6;                  // 8 waves
    float m[8], M[8];
    #pragma unroll
    for (int q = 0; q < 8; q++) {
        int i = t * 8 + q;
        unsigned long long p =
            __hip_atomic_load(&minpack[i], __ATOMIC_RELAXED, __HIP_MEMORY_SCOPE_AGENT);
        unsigned int mb =
            __hip_atomic_load(&maxbits[i], __ATOMIC_RELAXED, __HIP_MEMORY_SCOPE_AGENT);
        float dmin = (p == 0xFFFFFFFFFFFFFFFFull)
                       ? INF_F : sqrtf(__uint_as_float((unsigned)(p >> 32)));
        m[q] = (i == 0) ? INF_F : dmin;
        M[q] = (i == 0) ? -INF_F : sqrtf(__uint_as_float(mb));
    }
    float pmin[8], pmax[8];
    pmin[0] = m[0]; pmax[0] = M[0];
    #pragma unroll
    for (int q = 1; q < 8; q++) {
        pmin[q] = fminf(pmin[q - 1], m[q]);
        pmax[q] = fmaxf(pmax[q - 1], M[q]);
    }
    float wmin = pmin[7], wmax = pmax[7];
    #pragma unroll
    for (int off = 1; off < 64; off <<= 1) {
        float a = __shfl_up(wmin, off, 64);
        float b = __shfl_up(wmax, off, 64);
        if (lane >= off) { wmin = fminf(wmin, a); wmax = fmaxf(wmax, b); }
    }
    __shared__ float swmin[8], swmax[8];
    if (lane == 63) { swmin[wid8] = wmin; swmax[wid8] = wmax; }
    __syncthreads();
    float exwMin = INF_F, exwMax = -INF_F;
    for (int k = 0; k < wid8; k++) {
        exwMin = fminf(exwMin, swmin[k]);
        exwMax = fmaxf(exwMax, swmax[k]);
    }
    float upMin = __shfl_up(wmin, 1, 64);
    float upMax = __shfl_up(wmax, 1, 64);
    float exMin = fminf(exwMin, (lane > 0) ? upMin : INF_F);   // prefix over < t*8
    float exMax = fmaxf(exwMax, (lane > 0) ? upMax : -INF_F);

    int viol = B_N;
    #pragma unroll
    for (int q = 0; q < 8; q++) {
        int i = t * 8 + q;
        if (i >= 1) {
            float pm = (q == 0) ? exMin : fminf(exMin, pmin[q - 1]);
            float pM = (q == 0) ? exMax : fmaxf(exMax, pmax[q - 1]);
            float R  = (i == 1) ? 1.0f : (pm + pM) / 3.0f;
            if (!(m[q] > R) && i < viol) viol = i;
        }
    }
    int vw = viol;
    #pragma unroll
    for (int off = 32; off; off >>= 1) vw = min(vw, __shfl_down(vw, off, 64));
    __shared__ int svw[8];
    if (lane == 0) svw[wid8] = vw;
    __syncthreads();
    int s_star = B_N;
    for (int k = 0; k < 8; k++) s_star = min(s_star, svw[k]);

    for (int i = t; i < s_star; i += 512) out[i] = (float)labels[i];

    __shared__ float s_state[3];
    __shared__ int s_n;
    if (s_star < B_N && t == (s_star >> 3)) {
        int q = s_star & 7;
        float pm = (q == 0) ? exMin : fminf(exMin, pmin[q - 1]);
        float pM = (q == 0) ? exMax : fmaxf(exMax, pmax[q - 1]);
        float md = fminf(pm, m[q]);
        float Md = fmaxf(pM, M[q]);
        s_state[0] = md; s_state[1] = Md; s_state[2] = (md + Md) / 3.0f;
        s_n = s_star;
        unsigned long long p =
            __hip_atomic_load(&minpack[s_star], __ATOMIC_RELAXED, __HIP_MEMORY_SCOPE_AGENT);
        int j = (int)(unsigned)(p & 0xFFFFFFFFu);
        out[s_star] = (float)labels[j];
    }
    if (s_star >= B_N) return;

    for (int s = t; s < s_star; s += 512) ref_idx[s] = s;
    __syncthreads();

    __shared__ unsigned long long redp[512];
    __shared__ float redm[512];
    for (int i = s_star + 1; i < B_N; i++) {
        int n = s_n;
        const float* xi = x + (size_t)i * D_DIM;
        float ni = norms[i];
        unsigned long long mp = 0xFFFFFFFFFFFFFFFFull;
        float mx = -INF_F;
        for (int slot = t; slot < n; slot += 512) {
            int j = ref_idx[slot];
            const float* xj = x + (size_t)j * D_DIM;
            float dot = 0.f;
            for (int k = 0; k < D_DIM; k++) dot = fmaf(xi[k], xj[k], dot);
            float d = sqrtf(fmaxf(ni + norms[j] - 2.f * dot, 0.f));
            unsigned long long p =
                ((unsigned long long)__float_as_uint(d) << 32) | (unsigned)slot;
            if (p < mp) mp = p;
            mx = fmaxf(mx, d);
        }
        redp[t] = mp; redm[t] = mx;
        __syncthreads();
        for (int off = 256; off; off >>= 1) {
            if (t < off) {
                if (redp[t + off] < redp[t]) redp[t] = redp[t + off];
                redm[t] = fmaxf(redm[t], redm[t + off]);
            }
            __syncthreads();
        }
        if (t == 0) {
            unsigned long long p = redp[0];
            float min_act = __uint_as_float((unsigned)(p >> 32));
            int minslot   = (int)(unsigned)(p & 0xFFFFFFFFu);
            float max_act = redm[0];
            bool insert = (min_act > s_state[2]);
            int pred;
            if (insert) {
                ref_idx[n] = i;
                s_n = n + 1;
                pred = (min_act <= 0.0f) ? labels[ref_idx[minslot]] : labels[i];
            } else {
                pred = labels[ref_idx[minslot]];
            }
            float md = fminf(s_state[0], min_act);
            float Md = fmaxf(s_state[1], max_act);
            s_state[0] = md; s_state[1] = Md; s_state[2] = (md + Md) / 3.0f;
            out[i] = (float)pred;
        }
        __syncthreads();
    }
}

extern "C" void kernel_launch(void* const* d_in, const int* in_sizes, int n_in,
                              void* d_out, int out_size, void* d_ws, size_t ws_size,
                              hipStream_t stream) {
    const float* x      = (const float*)d_in[0];
    const int*   labels = (const int*)d_in[1];
    float*       out    = (float*)d_out;
    char* ws = (char*)d_ws;
    unsigned long long* minpack = (unsigned long long*)ws;
    unsigned int*       maxbits = (unsigned int*)(ws + 32768);
    float*              norms   = (float*)(ws + 49152);
    unsigned int*       done    = (unsigned int*)(ws + 65536);
    int*                ref_idx = (int*)(ws + 65600);
    unsigned char*      xq      = (unsigned char*)(ws + XQ_OFF);

    k_prep<<<B_N, 256, 0, stream>>>(x, xq, norms, minpack, maxbits, done);
    const int ntiles  = B_N / 128;                       // 32
    const int nblocks = ntiles * (ntiles + 1) / 2;       // 528
    k_pass1_fp8<<<nblocks, 512, 0, stream>>>(xq, norms, minpack, maxbits, done,
                                             x, labels, ref_idx, out);
}